// Round 10
// baseline (311.875 us; speedup 1.0000x reference)
//
#include <hip/hip_runtime.h>
#include <math.h>

#define HN 64
#define KNN 15
#define MAXT 768

__device__ __forceinline__ unsigned fenc(float f){
  unsigned u = __float_as_uint(f);
  return (u & 0x80000000u) ? ~u : (u | 0x80000000u);
}

__device__ __forceinline__ unsigned long long u64min(unsigned long long a, unsigned long long b){
  return a < b ? a : b;
}
__device__ __forceinline__ unsigned long long shfl_xor_u64(unsigned long long v, int mask){
  unsigned lo = (unsigned)v, hi = (unsigned)(v >> 32);
  lo = __shfl_xor((int)lo, mask, 64);
  hi = __shfl_xor((int)hi, mask, 64);
  return ((unsigned long long)hi << 32) | lo;
}

// Per-wave int64-vs-int32 edge detection + read.
__device__ __forceinline__ void edge_load(const void* ei, int E, int n, int e, int& r, int& c){
  const long long* L = (const long long*)ei;
  long long vr = L[e];
  bool ok = (vr >= 0 && vr < (long long)n);
  unsigned long long bal = __ballot(ok);
  unsigned long long act = __ballot(true);
  if (bal == act){
    r = (int)vr;
    c = (int)L[E + e];
  } else {
    const int* I = (const int*)ei;
    r = I[e];
    c = I[E + e];
  }
}

// mega: [0,nbY) y = x@Wt^T ; [nbY,nbY+nbC) edge row/col counts ; rest kNN.
__global__ void __launch_bounds__(256) k_mega(
    const float* __restrict__ x, const float* __restrict__ Wt, const void* ei,
    float* __restrict__ y, int* __restrict__ knn_cols,
    int* __restrict__ cnt, int* __restrict__ ccnt,
    int N, int E, int nbY, int nbC){
  __shared__ unsigned denc[4096];
  __shared__ unsigned long long mk[256];
  int b = blockIdx.x, t = threadIdx.x;
  if (b < nbY){
    int gid = b * 256 + t;
    if (gid < N * HN){
      int nn = gid >> 6, h = gid & 63;
      y[gid] = x[nn*3] * Wt[h*3] + x[nn*3+1] * Wt[h*3+1] + x[nn*3+2] * Wt[h*3+2];
    }
    return;
  }
  if (b < nbY + nbC){
    int e = (b - nbY) * 256 + t;
    if (e < E){
      int r, c;
      edge_load(ei, E, N, e, r, c);
      atomicAdd(&cnt[r], 1);
      atomicAdd(&ccnt[c], 1);
    }
    return;
  }
  // ---- kNN for node i ----
  int i = b - nbY - nbC;
  float xi0 = x[i*3], xi1 = x[i*3+1], xi2 = x[i*3+2];
  float sqi = xi0*xi0 + xi1*xi1 + xi2*xi2;
  unsigned long long best = ~0ULL;
  #pragma unroll
  for (int m = 0; m < 16; ++m){
    int j = t + 256*m;
    float a = x[j*3], bb = x[j*3+1], c = x[j*3+2];
    float sqj = a*a + bb*bb + c*c;
    float dot = xi0*a + xi1*bb + xi2*c;
    float d2 = (sqi - 2.0f*dot) + sqj;
    unsigned e = (j == i) ? 0xFFFFFFFFu : fenc(d2);
    denc[j] = e;
    best = u64min(best, ((unsigned long long)e << 32) | (unsigned)j);
  }
  mk[t] = best;
  __syncthreads();
  if (t >= 64) return;
  unsigned long long k0 = mk[t], k1 = mk[t+64], k2 = mk[t+128], k3 = mk[t+192];
  for (int m = 0; m < KNN; ++m){
    unsigned long long mm = u64min(u64min(k0, k1), u64min(k2, k3));
    #pragma unroll
    for (int off = 1; off < 64; off <<= 1)
      mm = u64min(mm, shfl_xor_u64(mm, off));
    int j = (int)(mm & 0xFFFFFFFFu);
    if (t == 0) knn_cols[i*KNN + m] = j;
    if ((j & 63) == t){
      int slot = j & 255;
      denc[j] = 0xFFFFFFFFu;
      unsigned long long nb = ~0ULL;
      #pragma unroll
      for (int m2 = 0; m2 < 16; ++m2){
        int jj = slot + 256*m2;
        nb = u64min(nb, ((unsigned long long)denc[jj] << 32) | (unsigned)jj);
      }
      int kreg = (j >> 6) & 3;
      if (kreg == 0) k0 = nb; else if (kreg == 1) k1 = nb;
      else if (kreg == 2) k2 = nb; else k3 = nb;
    }
  }
}

// two exclusive scans in one launch; also emits packed (base,len) info tables.
__global__ void k_scan2(const int* __restrict__ cnt, int* __restrict__ ptr,
                        const int* __restrict__ ccnt, int* __restrict__ cptr,
                        int2* __restrict__ rinfo, int2* __restrict__ cinfo, int n){
  __shared__ int part[1024];
  const int* src = (blockIdx.x == 0) ? cnt : ccnt;
  int* dst = (blockIdx.x == 0) ? ptr : cptr;
  int t = threadIdx.x;
  int base = t * 4;
  int a0 = src[base], a1 = src[base+1], a2 = src[base+2], a3 = src[base+3];
  int s = a0 + a1 + a2 + a3;
  part[t] = s;
  __syncthreads();
  for (int off = 1; off < 1024; off <<= 1){
    int v = (t >= off) ? part[t - off] : 0;
    __syncthreads();
    part[t] += v;
    __syncthreads();
  }
  int excl = part[t] - s;
  int v0 = excl, v1 = excl + a0, v2 = excl + a0 + a1, v3 = excl + a0 + a1 + a2;
  dst[base]   = v0;
  dst[base+1] = v1;
  dst[base+2] = v2;
  dst[base+3] = v3;
  if (t == 1023) dst[n] = part[1023];
  if (blockIdx.x == 0){
    rinfo[base]   = make_int2(v0 + KNN*base,     a0);
    rinfo[base+1] = make_int2(v1 + KNN*(base+1), a1);
    rinfo[base+2] = make_int2(v2 + KNN*(base+2), a2);
    rinfo[base+3] = make_int2(v3 + KNN*(base+3), a3);
  } else {
    cinfo[base]   = make_int2(v0, a0);
    cinfo[base+1] = make_int2(v1, a1);
    cinfo[base+2] = make_int2(v2, a2);
    cinfo[base+3] = make_int2(v3, a3);
  }
}

// fused extended-CSR fill: originals (atomic slots) + knn (deterministic slots)
__global__ void k_fill(const void* ei, const int* __restrict__ ptr,
                       int* __restrict__ fillo, const int* __restrict__ cnt,
                       const int* __restrict__ knncols, int* __restrict__ ecol,
                       int N, int E, int nbE){
  int b = blockIdx.x, t = threadIdx.x;
  if (b < nbE){
    int e = b * 256 + t;
    if (e < E){
      int r, c;
      edge_load(ei, E, N, e, r, c);
      int pos = ptr[r] + KNN*r + atomicAdd(&fillo[r], 1);
      ecol[pos] = c;
    }
  } else {
    int gid = (b - nbE) * 256 + t;
    if (gid < N * KNN){
      int i = gid / KNN, m = gid - i * KNN;
      ecol[ptr[i] + KNN*i + cnt[i] + m] = knncols[gid];
    }
  }
}

// fused DevConv-min + feats + q/k projections (agg/feats live in LDS only)
__global__ void k_dev(const int* __restrict__ ptr, const int* __restrict__ ecol,
                      const float* __restrict__ y, const float* __restrict__ bt,
                      const float* __restrict__ Wp, const float* __restrict__ bp,
                      const float* __restrict__ Wq, const float* __restrict__ Wk,
                      float* __restrict__ q, float* __restrict__ kf, int n){
  __shared__ float sag[256];
  __shared__ float sft[256];
  int t = threadIdx.x;
  int i = blockIdx.x * 4 + (t >> 6);
  int h = t & 63;
  int beg = ptr[i] + KNN*i;
  int end = ptr[i+1] + KNN*(i+1);
  float m = INFINITY;
  for (int idx = beg; idx < end; ++idx)
    m = fminf(m, y[ecol[idx]*HN + h]);
  sag[t] = y[i*HN + h] + bt[h] - m;
  __syncthreads();
  int nn = t >> 6;
  float acc = bp[h];
  #pragma unroll 8
  for (int c = 0; c < HN; ++c) acc += sag[nn*HN + c] * Wp[h*HN + c];
  sft[t] = acc;
  __syncthreads();
  float aq = 0.f, ak = 0.f;
  #pragma unroll 8
  for (int c = 0; c < HN; ++c){
    float f = sft[nn*HN + c];
    aq += f * Wq[h*HN + c];
    ak += f * Wk[h*HN + c];
  }
  size_t o = (size_t)blockIdx.x * 256 + t;
  q[o] = aq;
  kf[o] = ak;
}

// row-centric attention, lane-parallel over edges. Writes scp (col,val) CSR-order
// and csp (row,val) CSC-order.
__global__ void __launch_bounds__(256) k_rowattn(
    const int* __restrict__ ptr, const int2* __restrict__ cinfo,
    const int* __restrict__ ecol, const float* __restrict__ q,
    const float* __restrict__ kf, float* __restrict__ sval,
    int2* __restrict__ scp, int2* __restrict__ csp,
    int* __restrict__ cfill, int n){
  int t = threadIdx.x;
  int lane = t & 63;
  int r = blockIdx.x * 4 + (t >> 6);
  if (r >= n) return;
  int base = ptr[r];
  int deg = ptr[r+1] - base;
  if (deg == 0) return;
  int ebase = base + KNN*r;
  float4 qv[16];
  const float4* qr = (const float4*)(q + (size_t)r*HN);
  #pragma unroll
  for (int m = 0; m < 16; ++m) qv[m] = qr[m];
  float mx = -INFINITY;
  for (int s = lane; s < deg; s += 64){
    int c = ecol[ebase + s];
    const float4* kc = (const float4*)(kf + (size_t)c*HN);
    float acc = 0.f;
    #pragma unroll
    for (int m = 0; m < 16; ++m){
      float4 b = kc[m];
      acc += qv[m].x*b.x + qv[m].y*b.y + qv[m].z*b.z + qv[m].w*b.w;
    }
    sval[base + s] = acc;
    mx = fmaxf(mx, acc);
  }
  #pragma unroll
  for (int off = 1; off < 64; off <<= 1) mx = fmaxf(mx, __shfl_xor(mx, off, 64));
  float lsum = 0.f;
  for (int s = lane; s < deg; s += 64){
    float e = expf(sval[base + s] - mx);
    sval[base + s] = e;
    lsum += e;
  }
  #pragma unroll
  for (int off = 1; off < 64; off <<= 1) lsum += __shfl_xor(lsum, off, 64);
  for (int s = lane; s < deg; s += 64){
    float v = sval[base + s] / lsum;
    int c = ecol[ebase + s];
    scp[base + s] = make_int2(c, __float_as_int(v));
    int2 ci = cinfo[c];
    int pos = ci.x + atomicAdd(&cfill[c], 1);
    csp[pos] = make_int2(r, __float_as_int(v));
  }
}

// T-row k = dedup-merged concat over l in A-row(k) of csp-segment(l).
// Tag-write/read-back winner rounds (NO atomics). Round 0 assigns exactly one
// winner per DISTINCT address -> only round-0 winners recorded; later rounds
// accumulate duplicates into Drow. Loop control via __syncthreads_count
// (race-free; the old shared-flag protocol deadlocked).
__global__ void __launch_bounds__(256) k_tbuild(
    const int2* __restrict__ rinfo, const int* __restrict__ ecol,
    const int2* __restrict__ cinfo, const int2* __restrict__ csp,
    int2* __restrict__ tlist, int* __restrict__ tcnt, int n){
  __shared__ float Drow[4096];
  __shared__ int   tag[4096];
  __shared__ int   pre[65];
  __shared__ int   csrc[64];
  __shared__ int   wsum[4];
  int k = blockIdx.x, t = threadIdx.x, lane = t & 63, wid = t >> 6;
  float4* D4 = (float4*)Drow;
  float4 fz = {0.f, 0.f, 0.f, 0.f};
  #pragma unroll
  for (int j = 0; j < 4; ++j) D4[j*256 + t] = fz;
  int2 ri = rinfo[k];
  int nseg = min(ri.y, 64);
  if (t < 64){
    int v = 0, src = 0;
    if (lane < nseg){
      int c = ecol[ri.x + lane];
      int2 ci = cinfo[c];
      v = ci.y; src = ci.x;
    }
    csrc[lane] = src;
    int ps = v;
    #pragma unroll
    for (int off = 1; off < 64; off <<= 1){
      int o = __shfl_up(ps, off, 64);
      if (lane >= off) ps += o;
    }
    pre[lane + 1] = ps;
    if (lane == 0) pre[0] = 0;
  }
  __syncthreads();
  int total = min(pre[nseg], MAXT);
  // gather up to 3 entries per thread
  int er[3]; float ev[3]; bool edone[3];
  #pragma unroll
  for (int j = 0; j < 3; ++j){
    int d = t + 256*j;
    edone[j] = true;
    er[j] = 0; ev[j] = 0.f;
    if (d < total){
      int lo = 0, hi = nseg - 1;
      while (lo < hi){
        int mid = (lo + hi + 1) >> 1;
        if (pre[mid] <= d) lo = mid; else hi = mid - 1;
      }
      int2 e = csp[csrc[lo] + (d - pre[lo])];
      er[j] = e.x; ev[j] = __int_as_float(e.y); edone[j] = false;
    }
  }
  // dedup-accumulate rounds; per round winners have distinct r -> plain RMW safe
  int wr[3]; int wn = 0;
  int round = 0;
  while (true){
    #pragma unroll
    for (int j = 0; j < 3; ++j) if (!edone[j]) tag[er[j]] = t + 256*j;
    __syncthreads();
    bool any = false;
    #pragma unroll
    for (int j = 0; j < 3; ++j) if (!edone[j]){
      if (tag[er[j]] == t + 256*j){
        Drow[er[j]] += ev[j];
        edone[j] = true;
        if (round == 0) wr[wn++] = er[j];   // DISTINCT addresses only
      } else any = true;
    }
    ++round;
    if (__syncthreads_count(any ? 1 : 0) == 0) break;
    if (round >= MAXT) break;               // hang guard (never expected)
  }
  // block scan of winner counts -> compact slots (Drow holds full sums)
  int v = wn;
  #pragma unroll
  for (int off = 1; off < 64; off <<= 1){
    int o = __shfl_up(v, off, 64);
    if (lane >= off) v += o;
  }
  if (lane == 63) wsum[wid] = v;
  __syncthreads();
  int base0 = 0;
  #pragma unroll
  for (int w = 0; w < 4; ++w) if (w < wid) base0 += wsum[w];
  int excl = base0 + v - wn;
  int2* trow = tlist + (size_t)k * MAXT;
  #pragma unroll
  for (int j = 0; j < 3; ++j) if (j < wn)
    trow[excl + j] = make_int2(wr[j], __float_as_int(Drow[wr[j]]));
  if (t == 0) tcnt[k] = wsum[0] + wsum[1] + wsum[2] + wsum[3];
}

// A_s row i = sum_p v_p * T-row(k_p). ONE WAVE per row: no barriers, no atomics.
// Deduped T-rows guarantee distinct r across all entries -> plain LDS RMW safe.
__global__ void __launch_bounds__(64) k_papply(
    const int* __restrict__ ptr, const int2* __restrict__ scp,
    const int2* __restrict__ tlist, const int* __restrict__ tcnt,
    float* __restrict__ out, int n){
  __shared__ float orow[4096];
  int i = blockIdx.x, t = threadIdx.x;   // 64 threads
  float4* o4 = (float4*)orow;
  float4 z = {0.f, 0.f, 0.f, 0.f};
  #pragma unroll
  for (int j = 0; j < 16; ++j) o4[j*64 + t] = z;
  int base = ptr[i], len = ptr[i+1] - base;
  for (int p = 0; p < len; ++p){
    int2 kv = scp[base + p];
    int k = kv.x;
    float v = __int_as_float(kv.y);
    int tc = tcnt[k];
    const int2* trow = tlist + (size_t)k * MAXT;
    for (int d = t; d < tc; d += 64){
      int2 e = trow[d];
      orow[e.x] += v * __int_as_float(e.y);
    }
  }
  float4* dst = (float4*)(out + (size_t)i * n);
  #pragma unroll
  for (int j = 0; j < 16; ++j) dst[j*64 + t] = o4[j*64 + t];
}

extern "C" void kernel_launch(void* const* d_in, const int* in_sizes, int n_in,
                              void* d_out, int out_size, void* d_ws, size_t ws_size,
                              hipStream_t stream) {
  const float* x   = (const float*)d_in[0];
  const void*  ei  = d_in[1];
  const float* Wt  = (const float*)d_in[2];
  const float* bt  = (const float*)d_in[3];
  const float* Wp  = (const float*)d_in[4];
  const float* bp  = (const float*)d_in[5];
  const float* Wq  = (const float*)d_in[6];
  const float* Wk  = (const float*)d_in[7];
  float* out = (float*)d_out;

  const int N = in_sizes[0] / 3;         // 4096
  const int E = in_sizes[1] / 2;         // 65536

  char* p = (char*)d_ws;
  auto alloc = [&](size_t bytes) -> void* {
    void* r = (void*)p;
    p += (bytes + 255) & ~(size_t)255;
    return r;
  };
  int*      ctr     = (int*)  alloc((size_t)4*N*4);   // cnt, ccnt, cfill, fillo
  int*      cnt     = ctr;
  int*      ccnt    = ctr + N;
  int*      cfill   = ctr + 2*N;
  int*      fillo   = ctr + 3*N;

  float*    y       = (float*)alloc((size_t)N*HN*4);
  float*    q       = (float*)alloc((size_t)N*HN*4);
  float*    kf      = (float*)alloc((size_t)N*HN*4);
  int*      ptrb    = (int*)  alloc((size_t)(N+1)*4);
  int*      cptrb   = (int*)  alloc((size_t)(N+1)*4);
  int2*     rinfo   = (int2*) alloc((size_t)N*8);
  int2*     cinfo   = (int2*) alloc((size_t)N*8);
  int*      ecol    = (int*)  alloc((size_t)(E + N*KNN)*4);
  float*    sval    = (float*)alloc((size_t)E*4);
  int2*     scp     = (int2*) alloc((size_t)E*8);
  int2*     csp     = (int2*) alloc((size_t)E*8);
  int*      knncols = (int*)  alloc((size_t)N*KNN*4);
  int*      tcnt    = (int*)  alloc((size_t)N*4);
  int2*     tlist   = (int2*) alloc((size_t)N*MAXT*8);   // 25.2 MB padded

  hipMemsetAsync(ctr, 0, (size_t)4*N*4, stream);

  int nbY = (N*HN + 255)/256;            // 1024
  int nbC = (E + 255)/256;               // 256
  int nbK = (N*KNN + 255)/256;           // 240

  k_mega<<<nbY + nbC + N, 256, 0, stream>>>(x, Wt, ei, y, knncols, cnt, ccnt,
                                            N, E, nbY, nbC);
  k_scan2<<<2, 1024, 0, stream>>>(cnt, ptrb, ccnt, cptrb, rinfo, cinfo, N);
  k_fill<<<nbC + nbK, 256, 0, stream>>>(ei, ptrb, fillo, cnt, knncols, ecol,
                                        N, E, nbC);
  k_dev<<<N/4, 256, 0, stream>>>(ptrb, ecol, y, bt, Wp, bp, Wq, Wk, q, kf, N);
  k_rowattn<<<N/4, 256, 0, stream>>>(ptrb, cinfo, ecol, q, kf, sval, scp, csp,
                                     cfill, N);
  k_tbuild<<<N, 256, 0, stream>>>(rinfo, ecol, cinfo, csp, tlist, tcnt, N);
  k_papply<<<N, 64, 0, stream>>>(ptrb, scp, tlist, tcnt, out, N);
}

// Round 11
// 302.355 us; speedup vs baseline: 1.0315x; 1.0315x over previous
//
#include <hip/hip_runtime.h>
#include <math.h>

#define HN 64
#define KNN 15
#define MAXT 768

__device__ __forceinline__ unsigned fenc(float f){
  unsigned u = __float_as_uint(f);
  return (u & 0x80000000u) ? ~u : (u | 0x80000000u);
}

__device__ __forceinline__ unsigned long long u64min(unsigned long long a, unsigned long long b){
  return a < b ? a : b;
}
__device__ __forceinline__ unsigned long long shfl_xor_u64(unsigned long long v, int mask){
  unsigned lo = (unsigned)v, hi = (unsigned)(v >> 32);
  lo = __shfl_xor((int)lo, mask, 64);
  hi = __shfl_xor((int)hi, mask, 64);
  return ((unsigned long long)hi << 32) | lo;
}

// Per-wave int64-vs-int32 edge detection + read.
__device__ __forceinline__ void edge_load(const void* ei, int E, int n, int e, int& r, int& c){
  const long long* L = (const long long*)ei;
  long long vr = L[e];
  bool ok = (vr >= 0 && vr < (long long)n);
  unsigned long long bal = __ballot(ok);
  unsigned long long act = __ballot(true);
  if (bal == act){
    r = (int)vr;
    c = (int)L[E + e];
  } else {
    const int* I = (const int*)ei;
    r = I[e];
    c = I[E + e];
  }
}

// mega: [0,nbY) y = x@Wt^T ; [nbY,nbY+nbC) edge row/col counts ; rest kNN.
__global__ void __launch_bounds__(256) k_mega(
    const float* __restrict__ x, const float* __restrict__ Wt, const void* ei,
    float* __restrict__ y, int* __restrict__ knn_cols,
    int* __restrict__ cnt, int* __restrict__ ccnt,
    int N, int E, int nbY, int nbC){
  __shared__ unsigned denc[4096];
  __shared__ unsigned long long mk[256];
  int b = blockIdx.x, t = threadIdx.x;
  if (b < nbY){
    int gid = b * 256 + t;
    if (gid < N * HN){
      int nn = gid >> 6, h = gid & 63;
      y[gid] = x[nn*3] * Wt[h*3] + x[nn*3+1] * Wt[h*3+1] + x[nn*3+2] * Wt[h*3+2];
    }
    return;
  }
  if (b < nbY + nbC){
    int e = (b - nbY) * 256 + t;
    if (e < E){
      int r, c;
      edge_load(ei, E, N, e, r, c);
      atomicAdd(&cnt[r], 1);
      atomicAdd(&ccnt[c], 1);
    }
    return;
  }
  // ---- kNN for node i ----
  int i = b - nbY - nbC;
  float xi0 = x[i*3], xi1 = x[i*3+1], xi2 = x[i*3+2];
  float sqi = xi0*xi0 + xi1*xi1 + xi2*xi2;
  unsigned long long best = ~0ULL;
  #pragma unroll
  for (int m = 0; m < 16; ++m){
    int j = t + 256*m;
    float a = x[j*3], bb = x[j*3+1], c = x[j*3+2];
    float sqj = a*a + bb*bb + c*c;
    float dot = xi0*a + xi1*bb + xi2*c;
    float d2 = (sqi - 2.0f*dot) + sqj;
    unsigned e = (j == i) ? 0xFFFFFFFFu : fenc(d2);
    denc[j] = e;
    best = u64min(best, ((unsigned long long)e << 32) | (unsigned)j);
  }
  mk[t] = best;
  __syncthreads();
  if (t >= 64) return;
  unsigned long long k0 = mk[t], k1 = mk[t+64], k2 = mk[t+128], k3 = mk[t+192];
  for (int m = 0; m < KNN; ++m){
    unsigned long long mm = u64min(u64min(k0, k1), u64min(k2, k3));
    #pragma unroll
    for (int off = 1; off < 64; off <<= 1)
      mm = u64min(mm, shfl_xor_u64(mm, off));
    int j = (int)(mm & 0xFFFFFFFFu);
    if (t == 0) knn_cols[i*KNN + m] = j;
    if ((j & 63) == t){
      int slot = j & 255;
      denc[j] = 0xFFFFFFFFu;
      unsigned long long nb = ~0ULL;
      #pragma unroll
      for (int m2 = 0; m2 < 16; ++m2){
        int jj = slot + 256*m2;
        nb = u64min(nb, ((unsigned long long)denc[jj] << 32) | (unsigned)jj);
      }
      int kreg = (j >> 6) & 3;
      if (kreg == 0) k0 = nb; else if (kreg == 1) k1 = nb;
      else if (kreg == 2) k2 = nb; else k3 = nb;
    }
  }
}

// two exclusive scans in one launch; also emits packed (base,len) info tables.
__global__ void k_scan2(const int* __restrict__ cnt, int* __restrict__ ptr,
                        const int* __restrict__ ccnt, int* __restrict__ cptr,
                        int2* __restrict__ rinfo, int2* __restrict__ cinfo, int n){
  __shared__ int part[1024];
  const int* src = (blockIdx.x == 0) ? cnt : ccnt;
  int* dst = (blockIdx.x == 0) ? ptr : cptr;
  int t = threadIdx.x;
  int base = t * 4;
  int a0 = src[base], a1 = src[base+1], a2 = src[base+2], a3 = src[base+3];
  int s = a0 + a1 + a2 + a3;
  part[t] = s;
  __syncthreads();
  for (int off = 1; off < 1024; off <<= 1){
    int v = (t >= off) ? part[t - off] : 0;
    __syncthreads();
    part[t] += v;
    __syncthreads();
  }
  int excl = part[t] - s;
  int v0 = excl, v1 = excl + a0, v2 = excl + a0 + a1, v3 = excl + a0 + a1 + a2;
  dst[base]   = v0;
  dst[base+1] = v1;
  dst[base+2] = v2;
  dst[base+3] = v3;
  if (t == 1023) dst[n] = part[1023];
  if (blockIdx.x == 0){
    rinfo[base]   = make_int2(v0 + KNN*base,     a0);
    rinfo[base+1] = make_int2(v1 + KNN*(base+1), a1);
    rinfo[base+2] = make_int2(v2 + KNN*(base+2), a2);
    rinfo[base+3] = make_int2(v3 + KNN*(base+3), a3);
  } else {
    cinfo[base]   = make_int2(v0, a0);
    cinfo[base+1] = make_int2(v1, a1);
    cinfo[base+2] = make_int2(v2, a2);
    cinfo[base+3] = make_int2(v3, a3);
  }
}

// fused extended-CSR fill: originals (atomic slots) + knn (deterministic slots)
__global__ void k_fill(const void* ei, const int* __restrict__ ptr,
                       int* __restrict__ fillo, const int* __restrict__ cnt,
                       const int* __restrict__ knncols, int* __restrict__ ecol,
                       int N, int E, int nbE){
  int b = blockIdx.x, t = threadIdx.x;
  if (b < nbE){
    int e = b * 256 + t;
    if (e < E){
      int r, c;
      edge_load(ei, E, N, e, r, c);
      int pos = ptr[r] + KNN*r + atomicAdd(&fillo[r], 1);
      ecol[pos] = c;
    }
  } else {
    int gid = (b - nbE) * 256 + t;
    if (gid < N * KNN){
      int i = gid / KNN, m = gid - i * KNN;
      ecol[ptr[i] + KNN*i + cnt[i] + m] = knncols[gid];
    }
  }
}

// fused DevConv-min + feats + q/k projections (agg/feats live in LDS only)
__global__ void k_dev(const int* __restrict__ ptr, const int* __restrict__ ecol,
                      const float* __restrict__ y, const float* __restrict__ bt,
                      const float* __restrict__ Wp, const float* __restrict__ bp,
                      const float* __restrict__ Wq, const float* __restrict__ Wk,
                      float* __restrict__ q, float* __restrict__ kf, int n){
  __shared__ float sag[256];
  __shared__ float sft[256];
  int t = threadIdx.x;
  int i = blockIdx.x * 4 + (t >> 6);
  int h = t & 63;
  int beg = ptr[i] + KNN*i;
  int end = ptr[i+1] + KNN*(i+1);
  float m = INFINITY;
  for (int idx = beg; idx < end; ++idx)
    m = fminf(m, y[ecol[idx]*HN + h]);
  sag[t] = y[i*HN + h] + bt[h] - m;
  __syncthreads();
  int nn = t >> 6;
  float acc = bp[h];
  #pragma unroll 8
  for (int c = 0; c < HN; ++c) acc += sag[nn*HN + c] * Wp[h*HN + c];
  sft[t] = acc;
  __syncthreads();
  float aq = 0.f, ak = 0.f;
  #pragma unroll 8
  for (int c = 0; c < HN; ++c){
    float f = sft[nn*HN + c];
    aq += f * Wq[h*HN + c];
    ak += f * Wk[h*HN + c];
  }
  size_t o = (size_t)blockIdx.x * 256 + t;
  q[o] = aq;
  kf[o] = ak;
}

// row-centric attention, lane-parallel over edges. Writes scp (col,val) CSR-order
// and csp (row,val) CSC-order.
__global__ void __launch_bounds__(256) k_rowattn(
    const int* __restrict__ ptr, const int2* __restrict__ cinfo,
    const int* __restrict__ ecol, const float* __restrict__ q,
    const float* __restrict__ kf, float* __restrict__ sval,
    int2* __restrict__ scp, int2* __restrict__ csp,
    int* __restrict__ cfill, int n){
  int t = threadIdx.x;
  int lane = t & 63;
  int r = blockIdx.x * 4 + (t >> 6);
  if (r >= n) return;
  int base = ptr[r];
  int deg = ptr[r+1] - base;
  if (deg == 0) return;
  int ebase = base + KNN*r;
  float4 qv[16];
  const float4* qr = (const float4*)(q + (size_t)r*HN);
  #pragma unroll
  for (int m = 0; m < 16; ++m) qv[m] = qr[m];
  float mx = -INFINITY;
  for (int s = lane; s < deg; s += 64){
    int c = ecol[ebase + s];
    const float4* kc = (const float4*)(kf + (size_t)c*HN);
    float acc = 0.f;
    #pragma unroll
    for (int m = 0; m < 16; ++m){
      float4 b = kc[m];
      acc += qv[m].x*b.x + qv[m].y*b.y + qv[m].z*b.z + qv[m].w*b.w;
    }
    sval[base + s] = acc;
    mx = fmaxf(mx, acc);
  }
  #pragma unroll
  for (int off = 1; off < 64; off <<= 1) mx = fmaxf(mx, __shfl_xor(mx, off, 64));
  float lsum = 0.f;
  for (int s = lane; s < deg; s += 64){
    float e = expf(sval[base + s] - mx);
    sval[base + s] = e;
    lsum += e;
  }
  #pragma unroll
  for (int off = 1; off < 64; off <<= 1) lsum += __shfl_xor(lsum, off, 64);
  for (int s = lane; s < deg; s += 64){
    float v = sval[base + s] / lsum;
    int c = ecol[ebase + s];
    scp[base + s] = make_int2(c, __float_as_int(v));
    int2 ci = cinfo[c];
    int pos = ci.x + atomicAdd(&cfill[c], 1);
    csp[pos] = make_int2(r, __float_as_int(v));
  }
}

// T-row k = dedup-merged concat over l in A-row(k) of csp-segment(l),
// bucketed by output quarter (r>>10). Round-0 winners = distinct addresses.
__global__ void __launch_bounds__(256) k_tbuild(
    const int2* __restrict__ rinfo, const int* __restrict__ ecol,
    const int2* __restrict__ cinfo, const int2* __restrict__ csp,
    int2* __restrict__ tlist, int4* __restrict__ tqcnt, int n){
  __shared__ float Drow[4096];
  __shared__ int   tag[4096];
  __shared__ int   pre[65];
  __shared__ int   csrc[64];
  __shared__ int   wsumA[4];
  __shared__ int   wsumB[4];
  int k = blockIdx.x, t = threadIdx.x, lane = t & 63, wid = t >> 6;
  float4* D4 = (float4*)Drow;
  float4 fz = {0.f, 0.f, 0.f, 0.f};
  #pragma unroll
  for (int j = 0; j < 4; ++j) D4[j*256 + t] = fz;
  int2 ri = rinfo[k];
  int nseg = min(ri.y, 64);
  if (t < 64){
    int v = 0, src = 0;
    if (lane < nseg){
      int c = ecol[ri.x + lane];
      int2 ci = cinfo[c];
      v = ci.y; src = ci.x;
    }
    csrc[lane] = src;
    int ps = v;
    #pragma unroll
    for (int off = 1; off < 64; off <<= 1){
      int o = __shfl_up(ps, off, 64);
      if (lane >= off) ps += o;
    }
    pre[lane + 1] = ps;
    if (lane == 0) pre[0] = 0;
  }
  __syncthreads();
  int total = min(pre[nseg], MAXT);
  // gather up to 3 entries per thread
  int er[3]; float ev[3]; bool edone[3];
  #pragma unroll
  for (int j = 0; j < 3; ++j){
    int d = t + 256*j;
    edone[j] = true;
    er[j] = 0; ev[j] = 0.f;
    if (d < total){
      int lo = 0, hi = nseg - 1;
      while (lo < hi){
        int mid = (lo + hi + 1) >> 1;
        if (pre[mid] <= d) lo = mid; else hi = mid - 1;
      }
      int2 e = csp[csrc[lo] + (d - pre[lo])];
      er[j] = e.x; ev[j] = __int_as_float(e.y); edone[j] = false;
    }
  }
  // dedup-accumulate rounds; per round winners have distinct r -> plain RMW safe
  int wr[3]; int wn = 0;
  int round = 0;
  while (true){
    #pragma unroll
    for (int j = 0; j < 3; ++j) if (!edone[j]) tag[er[j]] = t + 256*j;
    __syncthreads();
    bool any = false;
    #pragma unroll
    for (int j = 0; j < 3; ++j) if (!edone[j]){
      if (tag[er[j]] == t + 256*j){
        Drow[er[j]] += ev[j];
        edone[j] = true;
        if (round == 0) wr[wn++] = er[j];   // DISTINCT addresses only
      } else any = true;
    }
    ++round;
    if (__syncthreads_count(any ? 1 : 0) == 0) break;
    if (round >= MAXT) break;               // hang guard
  }
  // quarter-bucketed compaction: dual packed 16-bit-field block scan (no atomics)
  int n0 = 0, n1 = 0, n2 = 0, n3 = 0;
  #pragma unroll
  for (int j = 0; j < 3; ++j) if (j < wn){
    int qq = wr[j] >> 10;
    if (qq == 0) ++n0; else if (qq == 1) ++n1; else if (qq == 2) ++n2; else ++n3;
  }
  int packA = n0 | (n1 << 16);
  int packB = n2 | (n3 << 16);
  int sA = packA, sB = packB;
  #pragma unroll
  for (int off = 1; off < 64; off <<= 1){
    int oA = __shfl_up(sA, off, 64);
    int oB = __shfl_up(sB, off, 64);
    if (lane >= off){ sA += oA; sB += oB; }
  }
  if (lane == 63){ wsumA[wid] = sA; wsumB[wid] = sB; }
  __syncthreads();
  int baseA = 0, baseB = 0;
  #pragma unroll
  for (int w = 0; w < 4; ++w) if (w < wid){ baseA += wsumA[w]; baseB += wsumB[w]; }
  int exclA = baseA + sA - packA;
  int exclB = baseB + sB - packB;
  int totalA = wsumA[0] + wsumA[1] + wsumA[2] + wsumA[3];
  int totalB = wsumB[0] + wsumB[1] + wsumB[2] + wsumB[3];
  int T0 = totalA & 0xffff, T1 = totalA >> 16;
  int T2 = totalB & 0xffff, T3 = totalB >> 16;
  int pos0 = (exclA & 0xffff);
  int pos1 = T0 + (exclA >> 16);
  int pos2 = T0 + T1 + (exclB & 0xffff);
  int pos3 = T0 + T1 + T2 + (exclB >> 16);
  int2* trow = tlist + (size_t)k * MAXT;
  #pragma unroll
  for (int j = 0; j < 3; ++j) if (j < wn){
    int r = wr[j];
    int qq = r >> 10;
    int pos;
    if (qq == 0) pos = pos0++; else if (qq == 1) pos = pos1++;
    else if (qq == 2) pos = pos2++; else pos = pos3++;
    trow[pos] = make_int2(r, __float_as_int(Drow[r]));
  }
  if (t == 0) tqcnt[k] = make_int4(T0, T1, T2, T3);
}

// A_s rows 2b,2b+1: 512 thr = 2 rows x 4 quarter-waves. Each wave owns a
// disjoint 1024-float LDS quarter: NO barriers, NO atomics, no races.
__global__ void __launch_bounds__(512) k_papply(
    const int* __restrict__ ptr, const int2* __restrict__ scp,
    const int2* __restrict__ tlist, const int4* __restrict__ tqcnt,
    float* __restrict__ out, int n){
  __shared__ float orow[2][4096];
  int t = threadIdx.x;
  int half = t >> 8;
  int wv = (t >> 6) & 3;
  int lane = t & 63;
  int i = blockIdx.x * 2 + half;
  float* my = orow[half];
  float4* oq = (float4*)(my + wv * 1024);
  float4 z = {0.f, 0.f, 0.f, 0.f};
  #pragma unroll
  for (int j = 0; j < 4; ++j) oq[j*64 + lane] = z;
  int base = ptr[i], len = ptr[i+1] - base;
  for (int p = 0; p < len; ++p){
    int2 kv = scp[base + p];
    int k = kv.x;
    float v = __int_as_float(kv.y);
    int4 tq = tqcnt[k];
    int off, cnt;
    if (wv == 0){ off = 0;                  cnt = tq.x; }
    else if (wv == 1){ off = tq.x;          cnt = tq.y; }
    else if (wv == 2){ off = tq.x + tq.y;   cnt = tq.z; }
    else { off = tq.x + tq.y + tq.z;        cnt = tq.w; }
    const int2* trow = tlist + (size_t)k * MAXT + off;
    for (int d = lane; d < cnt; d += 64){
      int2 e = trow[d];
      my[e.x] += v * __int_as_float(e.y);
    }
  }
  float4* dst = (float4*)(out + (size_t)i * n + wv * 1024);
  #pragma unroll
  for (int j = 0; j < 4; ++j) dst[j*64 + lane] = oq[j*64 + lane];
}

extern "C" void kernel_launch(void* const* d_in, const int* in_sizes, int n_in,
                              void* d_out, int out_size, void* d_ws, size_t ws_size,
                              hipStream_t stream) {
  const float* x   = (const float*)d_in[0];
  const void*  ei  = d_in[1];
  const float* Wt  = (const float*)d_in[2];
  const float* bt  = (const float*)d_in[3];
  const float* Wp  = (const float*)d_in[4];
  const float* bp  = (const float*)d_in[5];
  const float* Wq  = (const float*)d_in[6];
  const float* Wk  = (const float*)d_in[7];
  float* out = (float*)d_out;

  const int N = in_sizes[0] / 3;         // 4096
  const int E = in_sizes[1] / 2;         // 65536

  char* p = (char*)d_ws;
  auto alloc = [&](size_t bytes) -> void* {
    void* r = (void*)p;
    p += (bytes + 255) & ~(size_t)255;
    return r;
  };
  int*      ctr     = (int*)  alloc((size_t)4*N*4);   // cnt, ccnt, cfill, fillo
  int*      cnt     = ctr;
  int*      ccnt    = ctr + N;
  int*      cfill   = ctr + 2*N;
  int*      fillo   = ctr + 3*N;

  float*    y       = (float*)alloc((size_t)N*HN*4);
  float*    q       = (float*)alloc((size_t)N*HN*4);
  float*    kf      = (float*)alloc((size_t)N*HN*4);
  int*      ptrb    = (int*)  alloc((size_t)(N+1)*4);
  int*      cptrb   = (int*)  alloc((size_t)(N+1)*4);
  int2*     rinfo   = (int2*) alloc((size_t)N*8);
  int2*     cinfo   = (int2*) alloc((size_t)N*8);
  int*      ecol    = (int*)  alloc((size_t)(E + N*KNN)*4);
  float*    sval    = (float*)alloc((size_t)E*4);
  int2*     scp     = (int2*) alloc((size_t)E*8);
  int2*     csp     = (int2*) alloc((size_t)E*8);
  int*      knncols = (int*)  alloc((size_t)N*KNN*4);
  int4*     tqcnt   = (int4*) alloc((size_t)N*16);
  int2*     tlist   = (int2*) alloc((size_t)N*MAXT*8);   // 25.2 MB padded

  hipMemsetAsync(ctr, 0, (size_t)4*N*4, stream);

  int nbY = (N*HN + 255)/256;            // 1024
  int nbC = (E + 255)/256;               // 256
  int nbK = (N*KNN + 255)/256;           // 240

  k_mega<<<nbY + nbC + N, 256, 0, stream>>>(x, Wt, ei, y, knncols, cnt, ccnt,
                                            N, E, nbY, nbC);
  k_scan2<<<2, 1024, 0, stream>>>(cnt, ptrb, ccnt, cptrb, rinfo, cinfo, N);
  k_fill<<<nbC + nbK, 256, 0, stream>>>(ei, ptrb, fillo, cnt, knncols, ecol,
                                        N, E, nbC);
  k_dev<<<N/4, 256, 0, stream>>>(ptrb, ecol, y, bt, Wp, bp, Wq, Wk, q, kf, N);
  k_rowattn<<<N/4, 256, 0, stream>>>(ptrb, cinfo, ecol, q, kf, sval, scp, csp,
                                     cfill, N);
  k_tbuild<<<N, 256, 0, stream>>>(rinfo, ecol, cinfo, csp, tlist, tqcnt, N);
  k_papply<<<N/2, 512, 0, stream>>>(ptrb, scp, tlist, tqcnt, out, N);
}